// Round 1
// baseline (568.056 us; speedup 1.0000x reference)
//
#include <hip/hip_runtime.h>

#define B_ 4
#define T_ 2048
#define C_ 1024
#define H_ 16
#define D_ 64
#define M_ (B_*T_)      // 8192
#define N1_ (3*C_)      // 3072

typedef __bf16 bf16;
typedef __bf16 bf16x8 __attribute__((ext_vector_type(8)));
typedef __bf16 bf16x2 __attribute__((ext_vector_type(2)));
typedef float f32x4 __attribute__((ext_vector_type(4)));

// ---------------- fp32 -> bf16 conversion ----------------
__global__ void k_conv(const float* __restrict__ src, bf16* __restrict__ dst, int n) {
    int i = blockIdx.x * blockDim.x + threadIdx.x;
    if (i < n) dst[i] = (bf16)src[i];
}

// ---------------- GEMM: C[m][n] = sum_k A[m][k] * W[n][k] + bias[n] ----------------
// 128x128 tile per 256-thread block, BK=32, MFMA 16x16x32 bf16.
// LDS rows padded to 40 bf16 (80B) -> 2-way bank aliasing only (free).
template<bool OUTBF16>
__global__ __launch_bounds__(256) void k_gemm(const bf16* __restrict__ A,
                                              const bf16* __restrict__ W,
                                              const float* __restrict__ bias,
                                              void* __restrict__ Cout,
                                              int N, int K) {
    __shared__ __align__(16) bf16 As[128 * 40];
    __shared__ __align__(16) bf16 Ws[128 * 40];
    const int tid = threadIdx.x;
    const int lane16 = tid & 15;
    const int quad = (tid & 63) >> 4;
    const int wave = tid >> 6;
    const int wm = (wave >> 1) * 64, wn = (wave & 1) * 64;
    const long m0 = (long)blockIdx.y * 128;
    const long n0 = (long)blockIdx.x * 128;

    f32x4 acc[4][4] = {};

    // staging: 512 chunks of 16B (128 rows x 4 chunks), 2 per thread
    const int r0 = tid >> 2, ch0 = tid & 3;
    const int r1 = (tid + 256) >> 2, ch1 = tid & 3;

    for (int kt = 0; kt < K; kt += 32) {
        bf16x8 a0 = *(const bf16x8*)(A + (m0 + r0) * K + kt + ch0 * 8);
        bf16x8 a1 = *(const bf16x8*)(A + (m0 + r1) * K + kt + ch1 * 8);
        bf16x8 w0 = *(const bf16x8*)(W + (n0 + r0) * K + kt + ch0 * 8);
        bf16x8 w1 = *(const bf16x8*)(W + (n0 + r1) * K + kt + ch1 * 8);
        __syncthreads();
        *(bf16x8*)(As + r0 * 40 + ch0 * 8) = a0;
        *(bf16x8*)(As + r1 * 40 + ch1 * 8) = a1;
        *(bf16x8*)(Ws + r0 * 40 + ch0 * 8) = w0;
        *(bf16x8*)(Ws + r1 * 40 + ch1 * 8) = w1;
        __syncthreads();
        bf16x8 af[4], wf[4];
#pragma unroll
        for (int i = 0; i < 4; i++)
            af[i] = *(const bf16x8*)(As + (wm + i * 16 + lane16) * 40 + quad * 8);
#pragma unroll
        for (int i = 0; i < 4; i++)
            wf[i] = *(const bf16x8*)(Ws + (wn + i * 16 + lane16) * 40 + quad * 8);
#pragma unroll
        for (int mi = 0; mi < 4; mi++)
#pragma unroll
            for (int ni = 0; ni < 4; ni++)
                acc[mi][ni] = __builtin_amdgcn_mfma_f32_16x16x32_bf16(
                    af[mi], wf[ni], acc[mi][ni], 0, 0, 0);
    }

#pragma unroll
    for (int ni = 0; ni < 4; ni++) {
        long n = n0 + wn + ni * 16 + lane16;
        float bn = bias[n];
#pragma unroll
        for (int mi = 0; mi < 4; mi++) {
            long m = m0 + wm + mi * 16 + quad * 4;
#pragma unroll
            for (int r = 0; r < 4; r++) {
                float v = acc[mi][ni][r] + bn;
                if (OUTBF16) ((bf16*)Cout)[(m + r) * N + n] = (bf16)v;
                else         ((float*)Cout)[(m + r) * N + n] = v;
            }
        }
    }
}

// ---------------- RoPE for q,k; scatter to (B,H,T,D) ----------------
__global__ void k_rope(const bf16* __restrict__ qkv, bf16* __restrict__ qr,
                       bf16* __restrict__ kr) {
    int idx = blockIdx.x * 256 + threadIdx.x;    // ((b*H+h)*T + t)*32 + d2
    int d2 = idx & 31;
    int t = (idx >> 5) & (T_ - 1);
    int bh = idx >> 16;
    int b = bh >> 4, h = bh & 15;
    const bf16* row = qkv + ((long)(b * T_ + t)) * N1_;
    bf16x2 qp = *(const bf16x2*)(row + h * 64 + 2 * d2);
    bf16x2 kp = *(const bf16x2*)(row + 1024 + h * 64 + 2 * d2);
    float inv = exp2f(-0.415241011861f * (float)d2);  // 10000^(-2*d2/64)
    float ang = (float)t * inv;
    float s, c;
    sincosf(ang, &s, &c);
    float q0 = (float)qp[0], q1 = (float)qp[1];
    float k0 = (float)kp[0], k1 = (float)kp[1];
    bf16x2 qo, ko;
    qo[0] = (bf16)(q0 * c - q1 * s);
    qo[1] = (bf16)(q0 * s + q1 * c);
    ko[0] = (bf16)(k0 * c - k1 * s);
    ko[1] = (bf16)(k0 * s + k1 * c);
    long obase = ((long)bh * T_ + t) * 64 + 2 * d2;
    *(bf16x2*)(qr + obase) = qo;
    *(bf16x2*)(kr + obase) = ko;
}

// ---------------- V transpose to (B,H,D,T) ----------------
__global__ __launch_bounds__(256) void k_vtrans(const bf16* __restrict__ qkv,
                                                bf16* __restrict__ vt) {
    __shared__ __align__(16) bf16 tile[64 * 72];
    int bh = blockIdx.y;
    int t0 = blockIdx.x * 64;
    int b = bh >> 4, h = bh & 15;
    int tid = threadIdx.x;
    int tt = tid >> 2, seg = tid & 3;
    const bf16* src = qkv + ((long)(b * T_) + t0 + tt) * N1_ + 2048 + h * 64 + seg * 16;
    bf16x8 v0 = *(const bf16x8*)(src);
    bf16x8 v1 = *(const bf16x8*)(src + 8);
    *(bf16x8*)(tile + tt * 72 + seg * 16) = v0;
    *(bf16x8*)(tile + tt * 72 + seg * 16 + 8) = v1;
    __syncthreads();
    int d = tid >> 2;
    __align__(16) bf16 outv[16];
#pragma unroll
    for (int i = 0; i < 16; i++) outv[i] = tile[(seg * 16 + i) * 72 + d];
    bf16* dst = vt + ((long)bh * 64 + d) * T_ + t0 + seg * 16;
    *(bf16x8*)(dst) = *(const bf16x8*)(outv);
    *(bf16x8*)(dst + 8) = *(const bf16x8*)(outv + 8);
}

// ---------------- Flash attention: 1 wave per 16-row Q tile ----------------
__global__ __launch_bounds__(64) void k_flash(const bf16* __restrict__ qr,
                                              const bf16* __restrict__ kr,
                                              const bf16* __restrict__ vt,
                                              bf16* __restrict__ attn) {
    __shared__ __align__(16) bf16 Pl[16 * 40];
    const int qt = blockIdx.x, bh = blockIdx.y;
    const int b = bh >> 4, h = bh & 15;
    const int lane = threadIdx.x, lane16 = lane & 15, quad = lane >> 4;

    const bf16* qbase = qr + ((long)bh * T_ + qt * 16) * 64;
    bf16x8 qf0 = *(const bf16x8*)(qbase + lane16 * 64 + quad * 8);
    bf16x8 qf1 = *(const bf16x8*)(qbase + lane16 * 64 + 32 + quad * 8);

    float m_i[4], l_i[4];
    f32x4 o[4] = {};
#pragma unroll
    for (int r = 0; r < 4; r++) { m_i[r] = -1e30f; l_i[r] = 0.f; }

    const int nkv = (qt * 16 + 15) / 32 + 1;
    const bf16* kbase = kr + (long)bh * T_ * 64;
    const bf16* vbase = vt + (long)bh * 64 * T_;

    for (int kv = 0; kv < nkv; kv++) {
        int s0 = kv * 32;
        f32x4 sacc[2];
#pragma unroll
        for (int sh = 0; sh < 2; sh++) {
            const bf16* krow = kbase + (s0 + sh * 16 + lane16) * 64;
            bf16x8 kf0 = *(const bf16x8*)(krow + quad * 8);
            bf16x8 kf1 = *(const bf16x8*)(krow + 32 + quad * 8);
            f32x4 z = {};
            z = __builtin_amdgcn_mfma_f32_16x16x32_bf16(qf0, kf0, z, 0, 0, 0);
            sacc[sh] = __builtin_amdgcn_mfma_f32_16x16x32_bf16(qf1, kf1, z, 0, 0, 0);
        }
        float p0[4], p1[4], tm[4];
#pragma unroll
        for (int r = 0; r < 4; r++) {
            int mg = qt * 16 + quad * 4 + r;
            float v0 = sacc[0][r] * 0.125f;
            float v1 = sacc[1][r] * 0.125f;
            if (s0 + lane16 > mg) v0 = -1e30f;
            if (s0 + 16 + lane16 > mg) v1 = -1e30f;
            p0[r] = v0; p1[r] = v1;
            tm[r] = fmaxf(v0, v1);
        }
#pragma unroll
        for (int off = 1; off < 16; off <<= 1)
#pragma unroll
            for (int r = 0; r < 4; r++)
                tm[r] = fmaxf(tm[r], __shfl_xor(tm[r], off, 64));
        float alpha[4];
#pragma unroll
        for (int r = 0; r < 4; r++) {
            float mn = fmaxf(m_i[r], tm[r]);
            alpha[r] = __expf(m_i[r] - mn);
            m_i[r] = mn;
            p0[r] = __expf(p0[r] - mn);
            p1[r] = __expf(p1[r] - mn);
        }
        float ps[4];
#pragma unroll
        for (int r = 0; r < 4; r++) ps[r] = p0[r] + p1[r];
#pragma unroll
        for (int off = 1; off < 16; off <<= 1)
#pragma unroll
            for (int r = 0; r < 4; r++)
                ps[r] += __shfl_xor(ps[r], off, 64);
#pragma unroll
        for (int r = 0; r < 4; r++) l_i[r] = l_i[r] * alpha[r] + ps[r];
#pragma unroll
        for (int ct = 0; ct < 4; ct++)
#pragma unroll
            for (int r = 0; r < 4; r++) o[ct][r] *= alpha[r];

        __syncthreads();
#pragma unroll
        for (int r = 0; r < 4; r++) {
            Pl[(quad * 4 + r) * 40 + lane16] = (bf16)p0[r];
            Pl[(quad * 4 + r) * 40 + 16 + lane16] = (bf16)p1[r];
        }
        __syncthreads();
        bf16x8 pf = *(const bf16x8*)(Pl + lane16 * 40 + quad * 8);
#pragma unroll
        for (int ct = 0; ct < 4; ct++) {
            bf16x8 vf = *(const bf16x8*)(vbase + (ct * 16 + lane16) * T_ + s0 + quad * 8);
            o[ct] = __builtin_amdgcn_mfma_f32_16x16x32_bf16(pf, vf, o[ct], 0, 0, 0);
        }
    }

#pragma unroll
    for (int r = 0; r < 4; r++) {
        float invl = 1.0f / l_i[r];
        int mg = qt * 16 + quad * 4 + r;
        bf16* orow = attn + ((long)b * T_ + mg) * C_ + h * 64;
#pragma unroll
        for (int ct = 0; ct < 4; ct++)
            orow[ct * 16 + lane16] = (bf16)(o[ct][r] * invl);
    }
}

extern "C" void kernel_launch(void* const* d_in, const int* in_sizes, int n_in,
                              void* d_out, int out_size, void* d_ws, size_t ws_size,
                              hipStream_t stream) {
    const float* x     = (const float*)d_in[0];
    const float* qkv_w = (const float*)d_in[1];
    const float* qkv_b = (const float*)d_in[2];
    const float* out_w = (const float*)d_in[3];
    const float* out_b = (const float*)d_in[4];
    float* out = (float*)d_out;
    char* ws = (char*)d_ws;

    // workspace layout (bytes)
    bf16* xb   = (bf16*)(ws + 0);            // 16,777,216  x bf16 [8192][1024]
    bf16* wqkv = (bf16*)(ws + 16777216);     //  6,291,456  qkv_w bf16 [3072][1024]
    bf16* wout = (bf16*)(ws + 23068672);     //  2,097,152  out_w bf16 [1024][1024]
    bf16* qkv  = (bf16*)(ws + 25165824);     // 50,331,648  qkv bf16 [8192][3072]
    bf16* qr   = (bf16*)(ws + 75497472);     // 16,777,216  q roped (B,H,T,D)
    bf16* kr   = (bf16*)(ws + 92274688);     // 16,777,216  k roped (B,H,T,D)
    bf16* vt   = (bf16*)(ws + 109051904);    // 16,777,216  v transposed (B,H,D,T)
    bf16* attn = (bf16*)(ws + 125829120);    // 16,777,216  attn out bf16 [8192][1024]

    k_conv<<<M_ * C_ / 256, 256, 0, stream>>>(x, xb, M_ * C_);
    k_conv<<<N1_ * C_ / 256, 256, 0, stream>>>(qkv_w, wqkv, N1_ * C_);
    k_conv<<<C_ * C_ / 256, 256, 0, stream>>>(out_w, wout, C_ * C_);

    k_gemm<true><<<dim3(24, 64), 256, 0, stream>>>(xb, wqkv, qkv_b, (void*)qkv, N1_, C_);

    k_rope<<<16384, 256, 0, stream>>>(qkv, qr, kr);
    k_vtrans<<<dim3(32, 64), 256, 0, stream>>>(qkv, vt);

    k_flash<<<dim3(128, 64), 64, 0, stream>>>(qr, kr, vt, attn);

    k_gemm<false><<<dim3(8, 64), 256, 0, stream>>>(attn, wout, out_b, (void*)d_out, C_, C_);
}

// Round 2
// 444.290 us; speedup vs baseline: 1.2786x; 1.2786x over previous
//
#include <hip/hip_runtime.h>

#define B_ 4
#define T_ 2048
#define C_ 1024
#define H_ 16
#define D_ 64
#define M_ (B_*T_)      // 8192
#define N1_ (3*C_)      // 3072

typedef __bf16 bf16;
typedef __bf16 bf16x8 __attribute__((ext_vector_type(8)));
typedef __bf16 bf16x2 __attribute__((ext_vector_type(2)));
typedef float f32x4 __attribute__((ext_vector_type(4)));

// ---------------- fp32 -> bf16 conversion ----------------
__global__ void k_conv(const float* __restrict__ src, bf16* __restrict__ dst, int n) {
    int i = blockIdx.x * blockDim.x + threadIdx.x;
    if (i < n) dst[i] = (bf16)src[i];
}

// ---------------- GEMM: C[m][n] = sum_k A[m][k] * W[n][k] + bias[n] ----------------
// 128x128 tile per 256-thread block, BK=32, MFMA 16x16x32 bf16.
template<bool OUTBF16>
__global__ __launch_bounds__(256) void k_gemm(const bf16* __restrict__ A,
                                              const bf16* __restrict__ W,
                                              const float* __restrict__ bias,
                                              void* __restrict__ Cout,
                                              int N, int K) {
    __shared__ __align__(16) bf16 As[128 * 40];
    __shared__ __align__(16) bf16 Ws[128 * 40];
    const int tid = threadIdx.x;
    const int lane16 = tid & 15;
    const int quad = (tid & 63) >> 4;
    const int wave = tid >> 6;
    const int wm = (wave >> 1) * 64, wn = (wave & 1) * 64;
    const long m0 = (long)blockIdx.y * 128;
    const long n0 = (long)blockIdx.x * 128;

    f32x4 acc[4][4] = {};

    const int r0 = tid >> 2, ch0 = tid & 3;
    const int r1 = (tid + 256) >> 2, ch1 = tid & 3;

    for (int kt = 0; kt < K; kt += 32) {
        bf16x8 a0 = *(const bf16x8*)(A + (m0 + r0) * K + kt + ch0 * 8);
        bf16x8 a1 = *(const bf16x8*)(A + (m0 + r1) * K + kt + ch1 * 8);
        bf16x8 w0 = *(const bf16x8*)(W + (n0 + r0) * K + kt + ch0 * 8);
        bf16x8 w1 = *(const bf16x8*)(W + (n0 + r1) * K + kt + ch1 * 8);
        __syncthreads();
        *(bf16x8*)(As + r0 * 40 + ch0 * 8) = a0;
        *(bf16x8*)(As + r1 * 40 + ch1 * 8) = a1;
        *(bf16x8*)(Ws + r0 * 40 + ch0 * 8) = w0;
        *(bf16x8*)(Ws + r1 * 40 + ch1 * 8) = w1;
        __syncthreads();
        bf16x8 af[4], wf[4];
#pragma unroll
        for (int i = 0; i < 4; i++)
            af[i] = *(const bf16x8*)(As + (wm + i * 16 + lane16) * 40 + quad * 8);
#pragma unroll
        for (int i = 0; i < 4; i++)
            wf[i] = *(const bf16x8*)(Ws + (wn + i * 16 + lane16) * 40 + quad * 8);
#pragma unroll
        for (int mi = 0; mi < 4; mi++)
#pragma unroll
            for (int ni = 0; ni < 4; ni++)
                acc[mi][ni] = __builtin_amdgcn_mfma_f32_16x16x32_bf16(
                    af[mi], wf[ni], acc[mi][ni], 0, 0, 0);
    }

#pragma unroll
    for (int ni = 0; ni < 4; ni++) {
        long n = n0 + wn + ni * 16 + lane16;
        float bn = bias[n];
#pragma unroll
        for (int mi = 0; mi < 4; mi++) {
            long m = m0 + wm + mi * 16 + quad * 4;
#pragma unroll
            for (int r = 0; r < 4; r++) {
                float v = acc[mi][ni][r] + bn;
                if (OUTBF16) ((bf16*)Cout)[(m + r) * N + n] = (bf16)v;
                else         ((float*)Cout)[(m + r) * N + n] = v;
            }
        }
    }
}

// ---------------- RoPE for q,k; scatter to (B,H,T,D) ----------------
__global__ void k_rope(const bf16* __restrict__ qkv, bf16* __restrict__ qr,
                       bf16* __restrict__ kr) {
    int idx = blockIdx.x * 256 + threadIdx.x;    // ((b*H+h)*T + t)*32 + d2
    int d2 = idx & 31;
    int t = (idx >> 5) & (T_ - 1);
    int bh = idx >> 16;
    int b = bh >> 4, h = bh & 15;
    const bf16* row = qkv + ((long)(b * T_ + t)) * N1_;
    bf16x2 qp = *(const bf16x2*)(row + h * 64 + 2 * d2);
    bf16x2 kp = *(const bf16x2*)(row + 1024 + h * 64 + 2 * d2);
    float inv = exp2f(-0.415241011861f * (float)d2);  // 10000^(-2*d2/64)
    float ang = (float)t * inv;
    float s, c;
    sincosf(ang, &s, &c);
    float q0 = (float)qp[0], q1 = (float)qp[1];
    float k0 = (float)kp[0], k1 = (float)kp[1];
    bf16x2 qo, ko;
    qo[0] = (bf16)(q0 * c - q1 * s);
    qo[1] = (bf16)(q0 * s + q1 * c);
    ko[0] = (bf16)(k0 * c - k1 * s);
    ko[1] = (bf16)(k0 * s + k1 * c);
    long obase = ((long)bh * T_ + t) * 64 + 2 * d2;
    *(bf16x2*)(qr + obase) = qo;
    *(bf16x2*)(kr + obase) = ko;
}

// ---------------- V transpose to (B,H,D,T) ----------------
__global__ __launch_bounds__(256) void k_vtrans(const bf16* __restrict__ qkv,
                                                bf16* __restrict__ vt) {
    __shared__ __align__(16) bf16 tile[64 * 72];
    int bh = blockIdx.y;
    int t0 = blockIdx.x * 64;
    int b = bh >> 4, h = bh & 15;
    int tid = threadIdx.x;
    int tt = tid >> 2, seg = tid & 3;
    const bf16* src = qkv + ((long)(b * T_) + t0 + tt) * N1_ + 2048 + h * 64 + seg * 16;
    bf16x8 v0 = *(const bf16x8*)(src);
    bf16x8 v1 = *(const bf16x8*)(src + 8);
    *(bf16x8*)(tile + tt * 72 + seg * 16) = v0;
    *(bf16x8*)(tile + tt * 72 + seg * 16 + 8) = v1;
    __syncthreads();
    int d = tid >> 2;
    __align__(16) bf16 outv[16];
#pragma unroll
    for (int i = 0; i < 16; i++) outv[i] = tile[(seg * 16 + i) * 72 + d];
    bf16* dst = vt + ((long)bh * 64 + d) * T_ + t0 + seg * 16;
    *(bf16x8*)(dst) = *(const bf16x8*)(outv);
    *(bf16x8*)(dst + 8) = *(const bf16x8*)(outv + 8);
}

// ---------------- Flash attention: 256 threads, 64-row Q tile, 64-col KV tile ----------------
// Wave w handles Q rows [qt*64 + w*16, +16). K/V tiles staged in LDS, shared by 4 waves.
// All 4 waves need exactly qt+1 KV steps (KV tile == Q tile), so no wasted iterations.
__global__ __launch_bounds__(256) void k_flash(const bf16* __restrict__ qr,
                                               const bf16* __restrict__ kr,
                                               const bf16* __restrict__ vt,
                                               bf16* __restrict__ attn) {
    __shared__ __align__(16) bf16 Ks[64 * 72];
    __shared__ __align__(16) bf16 Vs[64 * 72];      // V^T tile: row=d, col=s_local
    __shared__ __align__(16) bf16 Pl[4 * 16 * 72];  // per-wave P staging

    const int qt = gridDim.x - 1 - blockIdx.x;  // longest blocks launch first
    const int bh = blockIdx.y;
    const int b = bh >> 4, h = bh & 15;
    const int tid = threadIdx.x;
    const int lane16 = tid & 15, quad = (tid & 63) >> 4;
    const int wave = tid >> 6;
    const int qrow0 = qt * 64 + wave * 16;

    // Q fragments (A-layout), held for the whole kernel
    const bf16* qbase = qr + ((long)bh * T_ + qrow0) * 64;
    bf16x8 qf0 = *(const bf16x8*)(qbase + lane16 * 64 + quad * 8);
    bf16x8 qf1 = *(const bf16x8*)(qbase + lane16 * 64 + 32 + quad * 8);

    float m_i[4], l_i[4];
    f32x4 o[4] = {};
#pragma unroll
    for (int r = 0; r < 4; r++) { m_i[r] = -1e30f; l_i[r] = 0.f; }

    const bf16* kbase = kr + (long)bh * T_ * 64;
    const bf16* vbase = vt + (long)bh * 64 * T_;
    bf16* Pw = Pl + wave * (16 * 72);

    const int srow = tid >> 3, sch = tid & 7;   // staging: 32 rows x 8 chunks, x2
    const int nkv = qt + 1;

    for (int kv = 0; kv < nkv; kv++) {
        const int s0 = kv * 64;
        // ---- stage K (64 s-rows x 64 d) and V^T (64 d-rows x 64 s) ----
        bf16x8 k0 = *(const bf16x8*)(kbase + (long)(s0 + srow) * 64 + sch * 8);
        bf16x8 k1 = *(const bf16x8*)(kbase + (long)(s0 + srow + 32) * 64 + sch * 8);
        bf16x8 v0 = *(const bf16x8*)(vbase + (long)srow * T_ + s0 + sch * 8);
        bf16x8 v1 = *(const bf16x8*)(vbase + (long)(srow + 32) * T_ + s0 + sch * 8);
        __syncthreads();   // prior iteration's LDS reads complete
        *(bf16x8*)(Ks + srow * 72 + sch * 8) = k0;
        *(bf16x8*)(Ks + (srow + 32) * 72 + sch * 8) = k1;
        *(bf16x8*)(Vs + srow * 72 + sch * 8) = v0;
        *(bf16x8*)(Vs + (srow + 32) * 72 + sch * 8) = v1;
        __syncthreads();

        // ---- QK^T: 16 rows x 64 cols, 4 col-tiles x 2 MFMAs ----
        f32x4 sacc[4];
#pragma unroll
        for (int ct = 0; ct < 4; ct++) {
            const bf16* krow = Ks + (ct * 16 + lane16) * 72;
            bf16x8 kf0 = *(const bf16x8*)(krow + quad * 8);
            bf16x8 kf1 = *(const bf16x8*)(krow + 32 + quad * 8);
            f32x4 z = {};
            z = __builtin_amdgcn_mfma_f32_16x16x32_bf16(qf0, kf0, z, 0, 0, 0);
            sacc[ct] = __builtin_amdgcn_mfma_f32_16x16x32_bf16(qf1, kf1, z, 0, 0, 0);
        }

        // ---- masked online softmax ----
        float p[4][4], tm[4];
#pragma unroll
        for (int r = 0; r < 4; r++) tm[r] = -1e30f;
#pragma unroll
        for (int ct = 0; ct < 4; ct++) {
            int cg = s0 + ct * 16 + lane16;
#pragma unroll
            for (int r = 0; r < 4; r++) {
                int mg = qrow0 + quad * 4 + r;
                float v = sacc[ct][r] * 0.125f;
                if (cg > mg) v = -1e30f;
                p[ct][r] = v;
                tm[r] = fmaxf(tm[r], v);
            }
        }
#pragma unroll
        for (int off = 1; off < 16; off <<= 1)
#pragma unroll
            for (int r = 0; r < 4; r++)
                tm[r] = fmaxf(tm[r], __shfl_xor(tm[r], off, 64));
        float alpha[4], ps[4];
#pragma unroll
        for (int r = 0; r < 4; r++) {
            float mn = fmaxf(m_i[r], tm[r]);
            alpha[r] = __expf(m_i[r] - mn);
            m_i[r] = mn;
            float s = 0.f;
#pragma unroll
            for (int ct = 0; ct < 4; ct++) { p[ct][r] = __expf(p[ct][r] - mn); s += p[ct][r]; }
            ps[r] = s;
        }
#pragma unroll
        for (int off = 1; off < 16; off <<= 1)
#pragma unroll
            for (int r = 0; r < 4; r++)
                ps[r] += __shfl_xor(ps[r], off, 64);
#pragma unroll
        for (int r = 0; r < 4; r++) l_i[r] = l_i[r] * alpha[r] + ps[r];
#pragma unroll
        for (int dt = 0; dt < 4; dt++)
#pragma unroll
            for (int r = 0; r < 4; r++) o[dt][r] *= alpha[r];

        // ---- P: C-layout -> A-layout via per-wave LDS (no block barrier) ----
#pragma unroll
        for (int ct = 0; ct < 4; ct++)
#pragma unroll
            for (int r = 0; r < 4; r++)
                Pw[(quad * 4 + r) * 72 + ct * 16 + lane16] = (bf16)p[ct][r];
        __builtin_amdgcn_wave_barrier();
        bf16x8 pf0 = *(const bf16x8*)(Pw + lane16 * 72 + quad * 8);
        bf16x8 pf1 = *(const bf16x8*)(Pw + lane16 * 72 + 32 + quad * 8);

        // ---- PV: o[dt] += P(16x64) * V(64x16) ----
#pragma unroll
        for (int dt = 0; dt < 4; dt++) {
            const bf16* vrow = Vs + (dt * 16 + lane16) * 72;
            bf16x8 vf0 = *(const bf16x8*)(vrow + quad * 8);
            bf16x8 vf1 = *(const bf16x8*)(vrow + 32 + quad * 8);
            o[dt] = __builtin_amdgcn_mfma_f32_16x16x32_bf16(pf0, vf0, o[dt], 0, 0, 0);
            o[dt] = __builtin_amdgcn_mfma_f32_16x16x32_bf16(pf1, vf1, o[dt], 0, 0, 0);
        }
    }

#pragma unroll
    for (int r = 0; r < 4; r++) {
        float invl = 1.0f / l_i[r];
        int mg = qrow0 + quad * 4 + r;
        bf16* orow = attn + ((long)b * T_ + mg) * C_ + h * 64;
#pragma unroll
        for (int dt = 0; dt < 4; dt++)
            orow[dt * 16 + lane16] = (bf16)(o[dt][r] * invl);
    }
}

extern "C" void kernel_launch(void* const* d_in, const int* in_sizes, int n_in,
                              void* d_out, int out_size, void* d_ws, size_t ws_size,
                              hipStream_t stream) {
    const float* x     = (const float*)d_in[0];
    const float* qkv_w = (const float*)d_in[1];
    const float* qkv_b = (const float*)d_in[2];
    const float* out_w = (const float*)d_in[3];
    const float* out_b = (const float*)d_in[4];
    char* ws = (char*)d_ws;

    bf16* xb   = (bf16*)(ws + 0);            // x bf16 [8192][1024]
    bf16* wqkv = (bf16*)(ws + 16777216);     // qkv_w bf16 [3072][1024]
    bf16* wout = (bf16*)(ws + 23068672);     // out_w bf16 [1024][1024]
    bf16* qkv  = (bf16*)(ws + 25165824);     // qkv bf16 [8192][3072]
    bf16* qr   = (bf16*)(ws + 75497472);     // q roped (B,H,T,D)
    bf16* kr   = (bf16*)(ws + 92274688);     // k roped (B,H,T,D)
    bf16* vt   = (bf16*)(ws + 109051904);    // v transposed (B,H,D,T)
    bf16* attn = (bf16*)(ws + 125829120);    // attn out bf16 [8192][1024]

    k_conv<<<M_ * C_ / 256, 256, 0, stream>>>(x, xb, M_ * C_);
    k_conv<<<N1_ * C_ / 256, 256, 0, stream>>>(qkv_w, wqkv, N1_ * C_);
    k_conv<<<C_ * C_ / 256, 256, 0, stream>>>(out_w, wout, C_ * C_);

    k_gemm<true><<<dim3(24, 64), 256, 0, stream>>>(xb, wqkv, qkv_b, (void*)qkv, N1_, C_);

    k_rope<<<16384, 256, 0, stream>>>(qkv, qr, kr);
    k_vtrans<<<dim3(32, 64), 256, 0, stream>>>(qkv, vt);

    k_flash<<<dim3(32, 64), 256, 0, stream>>>(qr, kr, vt, attn);

    k_gemm<false><<<dim3(8, 64), 256, 0, stream>>>(attn, wout, out_b, (void*)d_out, C_, C_);
}

// Round 3
// 316.968 us; speedup vs baseline: 1.7922x; 1.4017x over previous
//
#include <hip/hip_runtime.h>

#define B_ 4
#define T_ 2048
#define C_ 1024
#define H_ 16
#define D_ 64
#define M_ (B_*T_)      // 8192
#define N1_ (3*C_)      // 3072

typedef __bf16 bf16;
typedef __bf16 bf16x8 __attribute__((ext_vector_type(8)));
typedef __bf16 bf16x4 __attribute__((ext_vector_type(4)));
typedef __bf16 bf16x2 __attribute__((ext_vector_type(2)));
typedef float f32x4 __attribute__((ext_vector_type(4)));

#define GLOAD_LDS16(g, l) \
    __builtin_amdgcn_global_load_lds((const __attribute__((address_space(1))) void*)(g), \
                                     (__attribute__((address_space(3))) void*)(l), 16, 0, 0)

// ---------------- fp32 -> bf16 conversion ----------------
__global__ void k_conv(const float* __restrict__ src, bf16* __restrict__ dst, int n) {
    int i = blockIdx.x * blockDim.x + threadIdx.x;
    if (i < n) dst[i] = (bf16)src[i];
}

// ---------------- GEMM: C[m][n] = sum_k A[m][k] * W[n][k] + bias[n] ----------------
// 128x128 tile, BK=32, global_load_lds width-16 staging (m97 pattern), unpadded LDS.
template<bool OUTBF16>
__global__ __launch_bounds__(256) void k_gemm(const bf16* __restrict__ A,
                                              const bf16* __restrict__ W,
                                              const float* __restrict__ bias,
                                              void* __restrict__ Cout,
                                              int N, int K) {
    __shared__ __align__(16) bf16 As[128 * 32];
    __shared__ __align__(16) bf16 Ws[128 * 32];
    const int tid = threadIdx.x;
    const int lane16 = tid & 15;
    const int quad = (tid & 63) >> 4;
    const int wave = tid >> 6;
    const int wm = (wave >> 1) * 64, wn = (wave & 1) * 64;
    const long m0 = (long)blockIdx.y * 128;
    const long n0 = (long)blockIdx.x * 128;

    f32x4 acc[4][4] = {};

    // 16B chunk c: row = c>>2, seg = c&3. Thread stages chunks tid and tid+256.
    const int ra = tid >> 2, sa = tid & 3;
    const bf16* Ab0 = A + (m0 + ra) * K + sa * 8;
    const bf16* Ab1 = Ab0 + 64 * K;          // row + 64
    const bf16* Wb0 = W + (n0 + ra) * K + sa * 8;
    const bf16* Wb1 = Wb0 + 64 * K;
    bf16* Ad0 = As + tid * 8;                // chunk*16B
    bf16* Ad1 = As + tid * 8 + 2048;
    bf16* Wd0 = Ws + tid * 8;
    bf16* Wd1 = Ws + tid * 8 + 2048;

    for (int kt = 0; kt < K; kt += 32) {
        __syncthreads();                      // previous tile's frag reads done
        GLOAD_LDS16(Ab0 + kt, Ad0);
        GLOAD_LDS16(Ab1 + kt, Ad1);
        GLOAD_LDS16(Wb0 + kt, Wd0);
        GLOAD_LDS16(Wb1 + kt, Wd1);
        __syncthreads();                      // drains vmcnt (loads landed)
        bf16x8 af[4], wf[4];
#pragma unroll
        for (int i = 0; i < 4; i++)
            af[i] = *(const bf16x8*)(As + (wm + i * 16 + lane16) * 32 + quad * 8);
#pragma unroll
        for (int i = 0; i < 4; i++)
            wf[i] = *(const bf16x8*)(Ws + (wn + i * 16 + lane16) * 32 + quad * 8);
#pragma unroll
        for (int mi = 0; mi < 4; mi++)
#pragma unroll
            for (int ni = 0; ni < 4; ni++)
                acc[mi][ni] = __builtin_amdgcn_mfma_f32_16x16x32_bf16(
                    af[mi], wf[ni], acc[mi][ni], 0, 0, 0);
    }

#pragma unroll
    for (int ni = 0; ni < 4; ni++) {
        long n = n0 + wn + ni * 16 + lane16;
        float bn = bias[n];
#pragma unroll
        for (int mi = 0; mi < 4; mi++) {
            long m = m0 + wm + mi * 16 + quad * 4;
#pragma unroll
            for (int r = 0; r < 4; r++) {
                float v = acc[mi][ni][r] + bn;
                if (OUTBF16) ((bf16*)Cout)[(m + r) * N + n] = (bf16)v;
                else         ((float*)Cout)[(m + r) * N + n] = v;
            }
        }
    }
}

// ---------------- RoPE for q,k; scatter to (B,H,T,D) ----------------
__global__ void k_rope(const bf16* __restrict__ qkv, bf16* __restrict__ qr,
                       bf16* __restrict__ kr) {
    int idx = blockIdx.x * 256 + threadIdx.x;    // ((b*H+h)*T + t)*32 + d2
    int d2 = idx & 31;
    int t = (idx >> 5) & (T_ - 1);
    int bh = idx >> 16;
    int b = bh >> 4, h = bh & 15;
    const bf16* row = qkv + ((long)(b * T_ + t)) * N1_;
    bf16x2 qp = *(const bf16x2*)(row + h * 64 + 2 * d2);
    bf16x2 kp = *(const bf16x2*)(row + 1024 + h * 64 + 2 * d2);
    float inv = exp2f(-0.415241011861f * (float)d2);  // 10000^(-2*d2/64)
    float ang = (float)t * inv;
    float s, c;
    sincosf(ang, &s, &c);
    float q0 = (float)qp[0], q1 = (float)qp[1];
    float k0 = (float)kp[0], k1 = (float)kp[1];
    bf16x2 qo, ko;
    qo[0] = (bf16)(q0 * c - q1 * s);
    qo[1] = (bf16)(q0 * s + q1 * c);
    ko[0] = (bf16)(k0 * c - k1 * s);
    ko[1] = (bf16)(k0 * s + k1 * c);
    long obase = ((long)bh * T_ + t) * 64 + 2 * d2;
    *(bf16x2*)(qr + obase) = qo;
    *(bf16x2*)(kr + obase) = ko;
}

// ---------------- V transpose to (B,H,D,T) ----------------
__global__ __launch_bounds__(256) void k_vtrans(const bf16* __restrict__ qkv,
                                                bf16* __restrict__ vt) {
    __shared__ __align__(16) bf16 tile[64 * 72];
    int bh = blockIdx.y;
    int t0 = blockIdx.x * 64;
    int b = bh >> 4, h = bh & 15;
    int tid = threadIdx.x;
    int tt = tid >> 2, seg = tid & 3;
    const bf16* src = qkv + ((long)(b * T_) + t0 + tt) * N1_ + 2048 + h * 64 + seg * 16;
    bf16x8 v0 = *(const bf16x8*)(src);
    bf16x8 v1 = *(const bf16x8*)(src + 8);
    *(bf16x8*)(tile + tt * 72 + seg * 16) = v0;
    *(bf16x8*)(tile + tt * 72 + seg * 16 + 8) = v1;
    __syncthreads();
    int d = tid >> 2;
    __align__(16) bf16 outv[16];
#pragma unroll
    for (int i = 0; i < 16; i++) outv[i] = tile[(seg * 16 + i) * 72 + d];
    bf16* dst = vt + ((long)bh * 64 + d) * T_ + t0 + seg * 16;
    *(bf16x8*)(dst) = *(const bf16x8*)(outv);
    *(bf16x8*)(dst + 8) = *(const bf16x8*)(outv + 8);
}

// ---------------- Flash attention, S^T formulation ----------------
// 256 threads; wave w owns Q rows [qt*64+w*16, +16). Each block does Q-tile pair
// (qt, 31-qt) -> uniform 33 KV steps per block (perfect load balance).
// S^T = K*Q^T (C-layout: row=s, col=qrow=lane16) -> softmax reductions are
// in-lane over 16 regs + 2 cross-quad shuffle hops. P stored [qrow][s] with
// b64 writes; PV computes O^T = V^T * P^T; epilogue is b64 coalesced stores.
__global__ __launch_bounds__(256) void k_flash(const bf16* __restrict__ qr,
                                               const bf16* __restrict__ kr,
                                               const bf16* __restrict__ vt,
                                               bf16* __restrict__ attn) {
    __shared__ __align__(16) bf16 Ks[64 * 72];
    __shared__ __align__(16) bf16 Vs[64 * 72];       // V^T tile [d][s_local]
    __shared__ __align__(16) bf16 Pl[4 * 16 * 80];   // per-wave P [qrow][s], stride 80

    const int bh = blockIdx.y;
    const int b = bh >> 4, h = bh & 15;
    const int tid = threadIdx.x;
    const int lane16 = tid & 15, quad = (tid & 63) >> 4;
    const int wave = tid >> 6;
    const int srow = tid >> 3, sch = tid & 7;

    const bf16* kbase = kr + (long)bh * T_ * 64;
    const bf16* vbase = vt + (long)bh * 64 * T_;
    bf16* Pw = Pl + wave * (16 * 80);

    for (int phase = 0; phase < 2; ++phase) {
        const int qt = (phase == 0) ? (int)blockIdx.x : 31 - (int)blockIdx.x;
        const int qrow0 = qt * 64 + wave * 16;

        // Q as B-operand: B[k=quad*8+j][n=lane16] = Q[qrow0+lane16][kk*32+quad*8+j]
        const bf16* qbase = qr + ((long)bh * T_ + qrow0) * 64;
        bf16x8 qf0 = *(const bf16x8*)(qbase + lane16 * 64 + quad * 8);
        bf16x8 qf1 = *(const bf16x8*)(qbase + lane16 * 64 + 32 + quad * 8);

        float m_i = -1e30f, l_i = 0.f;
        f32x4 o[4] = {};   // O^T acc: row d = dt*16+quad*4+r, col qrow = lane16

        const int nkv = qt + 1;
        for (int kv = 0; kv < nkv; kv++) {
            const int s0 = kv * 64;
            bf16x8 k0 = *(const bf16x8*)(kbase + (long)(s0 + srow) * 64 + sch * 8);
            bf16x8 k1 = *(const bf16x8*)(kbase + (long)(s0 + srow + 32) * 64 + sch * 8);
            bf16x8 v0 = *(const bf16x8*)(vbase + (long)srow * T_ + s0 + sch * 8);
            bf16x8 v1 = *(const bf16x8*)(vbase + (long)(srow + 32) * T_ + s0 + sch * 8);
            __syncthreads();
            *(bf16x8*)(Ks + srow * 72 + sch * 8) = k0;
            *(bf16x8*)(Ks + (srow + 32) * 72 + sch * 8) = k1;
            *(bf16x8*)(Vs + srow * 72 + sch * 8) = v0;
            *(bf16x8*)(Vs + (srow + 32) * 72 + sch * 8) = v1;
            __syncthreads();

            // S^T = K·Q^T : 4 s-tiles, K-dim = 64 (2 chained MFMAs)
            f32x4 sacc[4];
#pragma unroll
            for (int ct = 0; ct < 4; ct++) {
                const bf16* krow = Ks + (ct * 16 + lane16) * 72;
                bf16x8 kf0 = *(const bf16x8*)(krow + quad * 8);
                bf16x8 kf1 = *(const bf16x8*)(krow + 32 + quad * 8);
                f32x4 z = {};
                z = __builtin_amdgcn_mfma_f32_16x16x32_bf16(kf0, qf0, z, 0, 0, 0);
                sacc[ct] = __builtin_amdgcn_mfma_f32_16x16x32_bf16(kf1, qf1, z, 0, 0, 0);
            }

            float p[4][4];
            if (s0 + 63 > qrow0) {           // diagonal tile: apply causal mask
                const int qg = qrow0 + lane16;
#pragma unroll
                for (int ct = 0; ct < 4; ct++)
#pragma unroll
                    for (int r = 0; r < 4; r++) {
                        int sg = s0 + ct * 16 + quad * 4 + r;
                        p[ct][r] = (sg > qg) ? -1e30f : sacc[ct][r] * 0.125f;
                    }
            } else {
#pragma unroll
                for (int ct = 0; ct < 4; ct++)
#pragma unroll
                    for (int r = 0; r < 4; r++)
                        p[ct][r] = sacc[ct][r] * 0.125f;
            }

            // row max: in-lane over 16, then 2 cross-quad hops
            float tm = p[0][0];
#pragma unroll
            for (int ct = 0; ct < 4; ct++)
#pragma unroll
                for (int r = 0; r < 4; r++) tm = fmaxf(tm, p[ct][r]);
            tm = fmaxf(tm, __shfl_xor(tm, 16, 64));
            tm = fmaxf(tm, __shfl_xor(tm, 32, 64));

            float mn = fmaxf(m_i, tm);
            float alpha = __expf(m_i - mn);
            m_i = mn;
            float ps = 0.f;
#pragma unroll
            for (int ct = 0; ct < 4; ct++)
#pragma unroll
                for (int r = 0; r < 4; r++) { p[ct][r] = __expf(p[ct][r] - mn); ps += p[ct][r]; }
            ps += __shfl_xor(ps, 16, 64);
            ps += __shfl_xor(ps, 32, 64);
            l_i = l_i * alpha + ps;
#pragma unroll
            for (int dt = 0; dt < 4; dt++)
#pragma unroll
                for (int r = 0; r < 4; r++) o[dt][r] *= alpha;

            // P^T C-layout -> P[qrow][s] in LDS: 4 vectorized b64 writes
#pragma unroll
            for (int ct = 0; ct < 4; ct++) {
                bf16x4 w;
                w[0] = (bf16)p[ct][0]; w[1] = (bf16)p[ct][1];
                w[2] = (bf16)p[ct][2]; w[3] = (bf16)p[ct][3];
                *(bf16x4*)(Pw + lane16 * 80 + ct * 16 + quad * 4) = w;
            }
            __builtin_amdgcn_wave_barrier();
            bf16x8 pf0 = *(const bf16x8*)(Pw + lane16 * 80 + quad * 8);
            bf16x8 pf1 = *(const bf16x8*)(Pw + lane16 * 80 + 32 + quad * 8);

            // O^T += V^T * P^T
#pragma unroll
            for (int dt = 0; dt < 4; dt++) {
                const bf16* vrow = Vs + (dt * 16 + lane16) * 72;
                bf16x8 vf0 = *(const bf16x8*)(vrow + quad * 8);
                bf16x8 vf1 = *(const bf16x8*)(vrow + 32 + quad * 8);
                o[dt] = __builtin_amdgcn_mfma_f32_16x16x32_bf16(vf0, pf0, o[dt], 0, 0, 0);
                o[dt] = __builtin_amdgcn_mfma_f32_16x16x32_bf16(vf1, pf1, o[dt], 0, 0, 0);
            }
        }

        // epilogue: lane holds O^T[d=dt*16+quad*4+r][qrow=lane16] -> b64 stores
        float invl = 1.0f / l_i;
        bf16* orow = attn + ((long)b * T_ + qrow0 + lane16) * C_ + h * 64 + quad * 4;
#pragma unroll
        for (int dt = 0; dt < 4; dt++) {
            bf16x4 w;
            w[0] = (bf16)(o[dt][0] * invl); w[1] = (bf16)(o[dt][1] * invl);
            w[2] = (bf16)(o[dt][2] * invl); w[3] = (bf16)(o[dt][3] * invl);
            *(bf16x4*)(orow + dt * 16) = w;
        }
    }
}

extern "C" void kernel_launch(void* const* d_in, const int* in_sizes, int n_in,
                              void* d_out, int out_size, void* d_ws, size_t ws_size,
                              hipStream_t stream) {
    const float* x     = (const float*)d_in[0];
    const float* qkv_w = (const float*)d_in[1];
    const float* qkv_b = (const float*)d_in[2];
    const float* out_w = (const float*)d_in[3];
    const float* out_b = (const float*)d_in[4];
    char* ws = (char*)d_ws;

    bf16* xb   = (bf16*)(ws + 0);            // x bf16 [8192][1024]
    bf16* wqkv = (bf16*)(ws + 16777216);     // qkv_w bf16 [3072][1024]
    bf16* wout = (bf16*)(ws + 23068672);     // out_w bf16 [1024][1024]
    bf16* qkv  = (bf16*)(ws + 25165824);     // qkv bf16 [8192][3072]
    bf16* qr   = (bf16*)(ws + 75497472);     // q roped (B,H,T,D)
    bf16* kr   = (bf16*)(ws + 92274688);     // k roped (B,H,T,D)
    bf16* vt   = (bf16*)(ws + 109051904);    // v transposed (B,H,D,T)
    bf16* attn = (bf16*)(ws + 125829120);    // attn out bf16 [8192][1024]

    k_conv<<<M_ * C_ / 256, 256, 0, stream>>>(x, xb, M_ * C_);
    k_conv<<<N1_ * C_ / 256, 256, 0, stream>>>(qkv_w, wqkv, N1_ * C_);
    k_conv<<<C_ * C_ / 256, 256, 0, stream>>>(out_w, wout, C_ * C_);

    k_gemm<true><<<dim3(24, 64), 256, 0, stream>>>(xb, wqkv, qkv_b, (void*)qkv, N1_, C_);

    k_rope<<<16384, 256, 0, stream>>>(qkv, qr, kr);
    k_vtrans<<<dim3(32, 64), 256, 0, stream>>>(qkv, vt);

    k_flash<<<dim3(16, 64), 256, 0, stream>>>(qr, kr, vt, attn);

    k_gemm<false><<<dim3(8, 64), 256, 0, stream>>>(attn, wout, out_b, (void*)d_out, C_, C_);
}

// Round 4
// 279.996 us; speedup vs baseline: 2.0288x; 1.1320x over previous
//
#include <hip/hip_runtime.h>

#define B_ 4
#define T_ 2048
#define C_ 1024
#define H_ 16
#define D_ 64
#define M_ (B_*T_)      // 8192
#define N1_ (3*C_)      // 3072

typedef __bf16 bf16;
typedef __bf16 bf16x8 __attribute__((ext_vector_type(8)));
typedef __bf16 bf16x4 __attribute__((ext_vector_type(4)));
typedef float f32x4 __attribute__((ext_vector_type(4)));

#define GLOAD_LDS16(g, l) \
    __builtin_amdgcn_global_load_lds((const __attribute__((address_space(1))) void*)(g), \
                                     (__attribute__((address_space(3))) void*)(l), 16, 0, 0)

// ---------------- fused fp32 -> bf16 conversion (x, qkv_w, out_w) ----------------
__global__ void k_conv3(const float* __restrict__ x, const float* __restrict__ w1,
                        const float* __restrict__ w2, bf16* __restrict__ xb,
                        bf16* __restrict__ wb1, bf16* __restrict__ wb2) {
    long i = ((long)blockIdx.x * 256 + threadIdx.x) * 4;
    const float* src; bf16* dst; long off;
    if (i < 8388608L)       { src = x;  dst = xb;  off = i; }
    else if (i < 11534336L) { src = w1; dst = wb1; off = i - 8388608L; }
    else                    { src = w2; dst = wb2; off = i - 11534336L; }
    float4 v = *(const float4*)(src + off);
    bf16x4 o; o[0] = (bf16)v.x; o[1] = (bf16)v.y; o[2] = (bf16)v.z; o[3] = (bf16)v.w;
    *(bf16x4*)(dst + off) = o;
}

// ---------------- QKV GEMM with fused bias + RoPE + layout scatter ----------------
// C[m][n] = x[m][:]·qkv_w[n][:] + b[n]; n<1024 -> RoPE -> qr (B,H,T,D);
// 1024..2047 -> RoPE -> kr; >=2048 -> vt (B,H,D,T) via b64 stores.
__global__ __launch_bounds__(256) void k_gemm_qkv(const bf16* __restrict__ A,
                                                  const bf16* __restrict__ W,
                                                  const float* __restrict__ bias,
                                                  bf16* __restrict__ qr,
                                                  bf16* __restrict__ kr,
                                                  bf16* __restrict__ vt) {
    __shared__ __align__(16) bf16 As[128 * 32];
    __shared__ __align__(16) bf16 Ws[128 * 32];
    const int tid = threadIdx.x;
    const int lane16 = tid & 15;
    const int quad = (tid & 63) >> 4;
    const int wave = tid >> 6;
    const int wm = (wave >> 1) * 64, wn = (wave & 1) * 64;
    const long m0 = (long)blockIdx.y * 128;
    const long n0 = (long)blockIdx.x * 128;
    const int K = C_;

    f32x4 acc[4][4] = {};

    const int ra = tid >> 2, sa = tid & 3;
    const bf16* Ab0 = A + (m0 + ra) * K + sa * 8;
    const bf16* Ab1 = Ab0 + 64 * K;
    const bf16* Wb0 = W + (n0 + ra) * K + sa * 8;
    const bf16* Wb1 = Wb0 + 64 * K;
    bf16* Ad0 = As + tid * 8;
    bf16* Ad1 = As + tid * 8 + 2048;
    bf16* Wd0 = Ws + tid * 8;
    bf16* Wd1 = Ws + tid * 8 + 2048;

    for (int kt = 0; kt < K; kt += 32) {
        __syncthreads();
        GLOAD_LDS16(Ab0 + kt, Ad0);
        GLOAD_LDS16(Ab1 + kt, Ad1);
        GLOAD_LDS16(Wb0 + kt, Wd0);
        GLOAD_LDS16(Wb1 + kt, Wd1);
        __syncthreads();
        bf16x8 af[4], wf[4];
#pragma unroll
        for (int i = 0; i < 4; i++)
            af[i] = *(const bf16x8*)(As + (wm + i * 16 + lane16) * 32 + quad * 8);
#pragma unroll
        for (int i = 0; i < 4; i++)
            wf[i] = *(const bf16x8*)(Ws + (wn + i * 16 + lane16) * 32 + quad * 8);
#pragma unroll
        for (int mi = 0; mi < 4; mi++)
#pragma unroll
            for (int ni = 0; ni < 4; ni++)
                acc[mi][ni] = __builtin_amdgcn_mfma_f32_16x16x32_bf16(
                    af[mi], wf[ni], acc[mi][ni], 0, 0, 0);
    }

    const int sect = (int)blockIdx.x >> 3;        // 0=Q 1=K 2=V
    const int bloc = (int)(m0 >> 11);             // batch index
    const int tloc0 = ((int)m0 & 2047) + wm + quad * 4;   // t at (mi=0,r=0)

    if (sect < 2) {
        bf16* dst = (sect == 0) ? qr : kr;
#pragma unroll
        for (int ni = 0; ni < 4; ni++) {
            int n = (int)n0 + wn + ni * 16 + lane16;
            int d = n & 63;
            int h = (n >> 6) & 15;
            float bn = bias[n];
            float inv = exp2f(-0.415241011861f * (float)(d >> 1));  // 10000^(-2*(d/2)/64)
            float sb, cb; sincosf((float)tloc0 * inv, &sb, &cb);
            float s1, c1; sincosf(inv, &s1, &c1);
            float s16, c16; sincosf(16.0f * inv, &s16, &c16);
            bf16* base = dst + ((long)(bloc * 16 + h) * T_) * 64 + d;
#pragma unroll
            for (int mi = 0; mi < 4; mi++) {
                float cm = cb, sm = sb;
#pragma unroll
                for (int r = 0; r < 4; r++) {
                    float v = acc[mi][ni][r] + bn;
                    float vp = __shfl_xor(v, 1, 64);
                    float outv = (d & 1) ? (vp * sm + v * cm) : (v * cm - vp * sm);
                    base[(long)(tloc0 + mi * 16 + r) * 64] = (bf16)outv;
                    float cm2 = cm * c1 - sm * s1;
                    float sm2 = sm * c1 + cm * s1;
                    cm = cm2; sm = sm2;
                }
                float cb2 = cb * c16 - sb * s16;
                float sb2 = sb * c16 + cb * s16;
                cb = cb2; sb = sb2;
            }
        }
    } else {
#pragma unroll
        for (int ni = 0; ni < 4; ni++) {
            int n = (int)n0 + wn + ni * 16 + lane16;
            int d = n & 63;
            int h = (n >> 6) & 15;
            float bn = bias[n];
            bf16* base = vt + ((long)(bloc * 16 + h) * 64 + d) * T_ + tloc0;
#pragma unroll
            for (int mi = 0; mi < 4; mi++) {
                bf16x4 w;
#pragma unroll
                for (int r = 0; r < 4; r++) w[r] = (bf16)(acc[mi][ni][r] + bn);
                *(bf16x4*)(base + mi * 16) = w;
            }
        }
    }
}

// ---------------- Output GEMM: out[m][n] = attn[m][:]·out_w[n][:] + b[n], fp32 out ----------------
__global__ __launch_bounds__(256) void k_gemm_out(const bf16* __restrict__ A,
                                                  const bf16* __restrict__ W,
                                                  const float* __restrict__ bias,
                                                  float* __restrict__ Cout) {
    __shared__ __align__(16) bf16 As[128 * 32];
    __shared__ __align__(16) bf16 Ws[128 * 32];
    const int tid = threadIdx.x;
    const int lane16 = tid & 15;
    const int quad = (tid & 63) >> 4;
    const int wave = tid >> 6;
    const int wm = (wave >> 1) * 64, wn = (wave & 1) * 64;
    const long m0 = (long)blockIdx.y * 128;
    const long n0 = (long)blockIdx.x * 128;
    const int K = C_, N = C_;

    f32x4 acc[4][4] = {};

    const int ra = tid >> 2, sa = tid & 3;
    const bf16* Ab0 = A + (m0 + ra) * K + sa * 8;
    const bf16* Ab1 = Ab0 + 64 * K;
    const bf16* Wb0 = W + (n0 + ra) * K + sa * 8;
    const bf16* Wb1 = Wb0 + 64 * K;
    bf16* Ad0 = As + tid * 8;
    bf16* Ad1 = As + tid * 8 + 2048;
    bf16* Wd0 = Ws + tid * 8;
    bf16* Wd1 = Ws + tid * 8 + 2048;

    for (int kt = 0; kt < K; kt += 32) {
        __syncthreads();
        GLOAD_LDS16(Ab0 + kt, Ad0);
        GLOAD_LDS16(Ab1 + kt, Ad1);
        GLOAD_LDS16(Wb0 + kt, Wd0);
        GLOAD_LDS16(Wb1 + kt, Wd1);
        __syncthreads();
        bf16x8 af[4], wf[4];
#pragma unroll
        for (int i = 0; i < 4; i++)
            af[i] = *(const bf16x8*)(As + (wm + i * 16 + lane16) * 32 + quad * 8);
#pragma unroll
        for (int i = 0; i < 4; i++)
            wf[i] = *(const bf16x8*)(Ws + (wn + i * 16 + lane16) * 32 + quad * 8);
#pragma unroll
        for (int mi = 0; mi < 4; mi++)
#pragma unroll
            for (int ni = 0; ni < 4; ni++)
                acc[mi][ni] = __builtin_amdgcn_mfma_f32_16x16x32_bf16(
                    af[mi], wf[ni], acc[mi][ni], 0, 0, 0);
    }

#pragma unroll
    for (int ni = 0; ni < 4; ni++) {
        long n = n0 + wn + ni * 16 + lane16;
        float bn = bias[n];
#pragma unroll
        for (int mi = 0; mi < 4; mi++) {
            long m = m0 + wm + mi * 16 + quad * 4;
#pragma unroll
            for (int r = 0; r < 4; r++)
                Cout[(m + r) * N + n] = acc[mi][ni][r] + bn;
        }
    }
}

// ---------------- Flash attention, S^T formulation, 2 row-groups per wave ----------------
// Block: 256 threads, 128-row Q tile; wave w owns rows (w)*16 and (w+4)*16 within tile.
// Tile pair (qt, 15-qt) -> uniform 36 KV steps. K/V frag LDS reads shared across groups.
// Global K/V loads for step kv+1 issued after barrier, overlapping compute of step kv.
__global__ __launch_bounds__(256) void k_flash(const bf16* __restrict__ qr,
                                               const bf16* __restrict__ kr,
                                               const bf16* __restrict__ vt,
                                               bf16* __restrict__ attn) {
    __shared__ __align__(16) bf16 Ks[64 * 72];
    __shared__ __align__(16) bf16 Vs[64 * 72];        // V^T tile [d][s_local]
    __shared__ __align__(16) bf16 Pl[8 * 16 * 72];    // (wave,g) P [qrow][s]

    const int bh = blockIdx.y;
    const int b = bh >> 4, h = bh & 15;
    const int tid = threadIdx.x;
    const int lane16 = tid & 15, quad = (tid & 63) >> 4;
    const int wave = tid >> 6;
    const int srow = tid >> 3, sch = tid & 7;

    const bf16* kbase = kr + (long)bh * T_ * 64;
    const bf16* vbase = vt + (long)bh * 64 * T_;
    bf16* Pw[2] = { Pl + (wave * 2 + 0) * (16 * 72), Pl + (wave * 2 + 1) * (16 * 72) };

    // preload KV tile s=0 (first tile of phase 0)
    bf16x8 k0 = *(const bf16x8*)(kbase + (long)srow * 64 + sch * 8);
    bf16x8 k1 = *(const bf16x8*)(kbase + (long)(srow + 32) * 64 + sch * 8);
    bf16x8 v0 = *(const bf16x8*)(vbase + (long)srow * T_ + sch * 8);
    bf16x8 v1 = *(const bf16x8*)(vbase + (long)(srow + 32) * T_ + sch * 8);

    for (int phase = 0; phase < 2; ++phase) {
        const int qt = (phase == 0) ? (int)blockIdx.x : 15 - (int)blockIdx.x;
        const int qrow0[2] = { qt * 128 + wave * 16, qt * 128 + (wave + 4) * 16 };

        bf16x8 qf[2][2];
#pragma unroll
        for (int g = 0; g < 2; g++) {
            const bf16* qb = qr + ((long)bh * T_ + qrow0[g]) * 64 + lane16 * 64;
            qf[g][0] = *(const bf16x8*)(qb + quad * 8);
            qf[g][1] = *(const bf16x8*)(qb + 32 + quad * 8);
        }

        float m_i[2] = { -1e30f, -1e30f }, l_i[2] = { 0.f, 0.f };
        f32x4 o[2][4] = {};

        const int nkv = 2 * qt + 2;
        for (int kv = 0; kv < nkv; kv++) {
            const int s0 = kv * 64;
            __syncthreads();
            *(bf16x8*)(Ks + srow * 72 + sch * 8) = k0;
            *(bf16x8*)(Ks + (srow + 32) * 72 + sch * 8) = k1;
            *(bf16x8*)(Vs + srow * 72 + sch * 8) = v0;
            *(bf16x8*)(Vs + (srow + 32) * 72 + sch * 8) = v1;
            __syncthreads();

            // prefetch next tile (next phase starts at s=0) — overlaps compute below
            {
                const int sn = (kv + 1 < nkv) ? (kv + 1) * 64 : 0;
                k0 = *(const bf16x8*)(kbase + (long)(sn + srow) * 64 + sch * 8);
                k1 = *(const bf16x8*)(kbase + (long)(sn + srow + 32) * 64 + sch * 8);
                v0 = *(const bf16x8*)(vbase + (long)srow * T_ + sn + sch * 8);
                v1 = *(const bf16x8*)(vbase + (long)(srow + 32) * T_ + sn + sch * 8);
            }

            // S^T = K·Q^T for both groups; K frags shared
            f32x4 sacc[2][4];
#pragma unroll
            for (int ct = 0; ct < 4; ct++) {
                const bf16* krow = Ks + (ct * 16 + lane16) * 72;
                bf16x8 kf0 = *(const bf16x8*)(krow + quad * 8);
                bf16x8 kf1 = *(const bf16x8*)(krow + 32 + quad * 8);
                f32x4 z0 = {}, z1 = {};
                z0 = __builtin_amdgcn_mfma_f32_16x16x32_bf16(kf0, qf[0][0], z0, 0, 0, 0);
                sacc[0][ct] = __builtin_amdgcn_mfma_f32_16x16x32_bf16(kf1, qf[0][1], z0, 0, 0, 0);
                z1 = __builtin_amdgcn_mfma_f32_16x16x32_bf16(kf0, qf[1][0], z1, 0, 0, 0);
                sacc[1][ct] = __builtin_amdgcn_mfma_f32_16x16x32_bf16(kf1, qf[1][1], z1, 0, 0, 0);
            }

            // online softmax per group (independent chains -> ILP)
            float p[2][4][4];
#pragma unroll
            for (int g = 0; g < 2; g++) {
                if (s0 + 63 > qrow0[g]) {
                    const int qg = qrow0[g] + lane16;
#pragma unroll
                    for (int ct = 0; ct < 4; ct++)
#pragma unroll
                        for (int r = 0; r < 4; r++) {
                            int sg = s0 + ct * 16 + quad * 4 + r;
                            p[g][ct][r] = (sg > qg) ? -1e30f : sacc[g][ct][r] * 0.125f;
                        }
                } else {
#pragma unroll
                    for (int ct = 0; ct < 4; ct++)
#pragma unroll
                        for (int r = 0; r < 4; r++)
                            p[g][ct][r] = sacc[g][ct][r] * 0.125f;
                }
                float tm = p[g][0][0];
#pragma unroll
                for (int ct = 0; ct < 4; ct++)
#pragma unroll
                    for (int r = 0; r < 4; r++) tm = fmaxf(tm, p[g][ct][r]);
                tm = fmaxf(tm, __shfl_xor(tm, 16, 64));
                tm = fmaxf(tm, __shfl_xor(tm, 32, 64));
                float mn = fmaxf(m_i[g], tm);
                float alpha = __expf(m_i[g] - mn);
                m_i[g] = mn;
                float ps = 0.f;
#pragma unroll
                for (int ct = 0; ct < 4; ct++)
#pragma unroll
                    for (int r = 0; r < 4; r++) {
                        p[g][ct][r] = __expf(p[g][ct][r] - mn);
                        ps += p[g][ct][r];
                    }
                ps += __shfl_xor(ps, 16, 64);
                ps += __shfl_xor(ps, 32, 64);
                l_i[g] = l_i[g] * alpha + ps;
#pragma unroll
                for (int dt = 0; dt < 4; dt++)
#pragma unroll
                    for (int r = 0; r < 4; r++) o[g][dt][r] *= alpha;
            }

            // P -> [qrow][s] per-wave LDS (b64 writes), wave-local ordering only
#pragma unroll
            for (int g = 0; g < 2; g++)
#pragma unroll
                for (int ct = 0; ct < 4; ct++) {
                    bf16x4 w;
                    w[0] = (bf16)p[g][ct][0]; w[1] = (bf16)p[g][ct][1];
                    w[2] = (bf16)p[g][ct][2]; w[3] = (bf16)p[g][ct][3];
                    *(bf16x4*)(Pw[g] + lane16 * 72 + ct * 16 + quad * 4) = w;
                }
            __builtin_amdgcn_wave_barrier();
            bf16x8 pf[2][2];
#pragma unroll
            for (int g = 0; g < 2; g++) {
                pf[g][0] = *(const bf16x8*)(Pw[g] + lane16 * 72 + quad * 8);
                pf[g][1] = *(const bf16x8*)(Pw[g] + lane16 * 72 + 32 + quad * 8);
            }

            // O^T += V^T·P^T ; V frags shared across groups
#pragma unroll
            for (int dt = 0; dt < 4; dt++) {
                const bf16* vrow = Vs + (dt * 16 + lane16) * 72;
                bf16x8 vf0 = *(const bf16x8*)(vrow + quad * 8);
                bf16x8 vf1 = *(const bf16x8*)(vrow + 32 + quad * 8);
                o[0][dt] = __builtin_amdgcn_mfma_f32_16x16x32_bf16(vf0, pf[0][0], o[0][dt], 0, 0, 0);
                o[0][dt] = __builtin_amdgcn_mfma_f32_16x16x32_bf16(vf1, pf[0][1], o[0][dt], 0, 0, 0);
                o[1][dt] = __builtin_amdgcn_mfma_f32_16x16x32_bf16(vf0, pf[1][0], o[1][dt], 0, 0, 0);
                o[1][dt] = __builtin_amdgcn_mfma_f32_16x16x32_bf16(vf1, pf[1][1], o[1][dt], 0, 0, 0);
            }
        }

        // epilogue: O^T[d][qrow] -> b64 coalesced-ish stores
#pragma unroll
        for (int g = 0; g < 2; g++) {
            float invl = 1.0f / l_i[g];
            bf16* orow = attn + ((long)b * T_ + qrow0[g] + lane16) * C_ + h * 64 + quad * 4;
#pragma unroll
            for (int dt = 0; dt < 4; dt++) {
                bf16x4 w;
                w[0] = (bf16)(o[g][dt][0] * invl); w[1] = (bf16)(o[g][dt][1] * invl);
                w[2] = (bf16)(o[g][dt][2] * invl); w[3] = (bf16)(o[g][dt][3] * invl);
                *(bf16x4*)(orow + dt * 16) = w;
            }
        }
    }
}

extern "C" void kernel_launch(void* const* d_in, const int* in_sizes, int n_in,
                              void* d_out, int out_size, void* d_ws, size_t ws_size,
                              hipStream_t stream) {
    const float* x     = (const float*)d_in[0];
    const float* qkv_w = (const float*)d_in[1];
    const float* qkv_b = (const float*)d_in[2];
    const float* out_w = (const float*)d_in[3];
    const float* out_b = (const float*)d_in[4];
    char* ws = (char*)d_ws;

    bf16* xb   = (bf16*)(ws + 0);            // x bf16 [8192][1024]       16.8 MB
    bf16* wqkv = (bf16*)(ws + 16777216);     // qkv_w bf16 [3072][1024]    6.3 MB
    bf16* wout = (bf16*)(ws + 23068672);     // out_w bf16 [1024][1024]    2.1 MB
    bf16* qr   = (bf16*)(ws + 25165824);     // q roped (B,H,T,D)         16.8 MB
    bf16* kr   = (bf16*)(ws + 41943040);     // k roped (B,H,T,D)         16.8 MB
    bf16* vt   = (bf16*)(ws + 58720256);     // v transposed (B,H,D,T)    16.8 MB
    bf16* attn = (bf16*)(ws + 75497472);     // attn out bf16 [8192][1024]16.8 MB

    k_conv3<<<12288, 256, 0, stream>>>(x, qkv_w, out_w, xb, wqkv, wout);

    k_gemm_qkv<<<dim3(24, 64), 256, 0, stream>>>(xb, wqkv, qkv_b, qr, kr, vt);

    k_flash<<<dim3(8, 64), 256, 0, stream>>>(qr, kr, vt, attn);

    k_gemm_out<<<dim3(8, 64), 256, 0, stream>>>(attn, wout, out_b, (float*)d_out);
}